// Round 4
// baseline (556.529 us; speedup 1.0000x reference)
//
#include <hip/hip_runtime.h>
#include <hip/hip_bf16.h>

// ---------------------------------------------------------------------------
// LucasKANLayer fused: y[b,o] = sum_i sum_d L_d(tanh(x[b,i])) * C[i,o,d]
// R4: NO LDS, NO barriers in the K-loop. B-fragments and t-values are loaded
// global->register with 1-step register prefetch (compiler places vmcnt waits
// before first use -> true async pipeline, sidesteps the global_load_lds
// vmcnt(0)-at-barrier drain that capped R1-R3 at ~800 TF).
// Wave tile 64m x 64n, distinct n per wave (block 64m x 256n) -> zero
// cross-wave sharing. grid.x = n-block so each XCD L2-caches one 4 MiB panel.
// ---------------------------------------------------------------------------

typedef __attribute__((ext_vector_type(8)))  short  short8;    // bf16x8 MFMA frag
typedef __attribute__((ext_vector_type(4)))  unsigned short ushort4v;
typedef __attribute__((ext_vector_type(8)))  unsigned short ushort8;
typedef __attribute__((ext_vector_type(4)))  float  float4v;
typedef __attribute__((ext_vector_type(4)))  unsigned int uint4v;

#define M_DIM 8192
#define I_DIM 1024
#define O_DIM 1024
#define K_DIM 8192   // I_DIM * 8
#define BM 64        // block m
#define BN 256       // block n (4 waves x 64n, disjoint)
#define BK 64        // 8 i-values per K-step
#define NSTEP (K_DIM / BK)

// round-to-nearest-even fp32 -> bf16 bits (prep kernel)
__device__ __forceinline__ unsigned short f2bf(float f) {
    unsigned int u = __float_as_uint(f);
    u += 0x7FFFu + ((u >> 16) & 1u);
    return (unsigned short)(u >> 16);
}

// ---- fused prep: T[b][i] = bf16(tanh(x)); Bt[o][i*8+d] = bf16(coeffs) ----
__global__ __launch_bounds__(256) void prep_kernel(const float* __restrict__ x,
                                                   const float* __restrict__ c,
                                                   unsigned short* __restrict__ T,
                                                   unsigned short* __restrict__ Bt) {
    int bid = blockIdx.x;
    if (bid < (M_DIM * I_DIM) / (4 * 256)) {
        // tanh part: 4 elements/thread
        int idx = (bid * 256 + threadIdx.x) * 4;
        float4v v = *(const float4v*)(x + idx);
        ushort4v o;
        o[0] = f2bf(tanhf(v[0]));
        o[1] = f2bf(tanhf(v[1]));
        o[2] = f2bf(tanhf(v[2]));
        o[3] = f2bf(tanhf(v[3]));
        *(ushort4v*)(T + idx) = o;
    } else {
        // coeff transpose part: one (i,o) per thread
        int idx = (bid - (M_DIM * I_DIM) / (4 * 256)) * 256 + threadIdx.x;
        int i = idx >> 10;
        int o = idx & 1023;
        const float* src = c + (size_t)i * 8192 + o * 8;
        float4v lo = *(const float4v*)(src);
        float4v hi = *(const float4v*)(src + 4);
        ushort8 v;
        v[0] = f2bf(lo[0]); v[1] = f2bf(lo[1]); v[2] = f2bf(lo[2]); v[3] = f2bf(lo[3]);
        v[4] = f2bf(hi[0]); v[5] = f2bf(hi[1]); v[6] = f2bf(hi[2]); v[7] = f2bf(hi[3]);
        *(ushort8*)(Bt + (size_t)o * K_DIM + i * 8) = v;
    }
}

// Lucas A-fragment from one bf16 t (bits in tb): {2, t, L2..L7} packed bf16x8.
// Round-half-up pack via +0x8000 and v_perm (numerics verified R2/R3).
__device__ __forceinline__ short8 lucas_frag(unsigned int tb) {
    const float t = __uint_as_float(tb << 16);
    const float L2v = fmaf(t, t, 2.0f);
    const float L3v = fmaf(t, L2v, t);
    const float L4v = fmaf(t, L3v, L2v);
    const float L5v = fmaf(t, L4v, L3v);
    const float L6v = fmaf(t, L5v, L4v);
    const float L7v = fmaf(t, L6v, L5v);
    const unsigned int u2 = __float_as_uint(L2v) + 0x8000u;
    const unsigned int u3 = __float_as_uint(L3v) + 0x8000u;
    const unsigned int u4 = __float_as_uint(L4v) + 0x8000u;
    const unsigned int u5 = __float_as_uint(L5v) + 0x8000u;
    const unsigned int u6 = __float_as_uint(L6v) + 0x8000u;
    const unsigned int u7 = __float_as_uint(L7v) + 0x8000u;
    union { uint4v u; short8 s; } r;
    r.u[0] = 0x4000u | (tb << 16);                       // L0=2.0, L1=t
    r.u[1] = __builtin_amdgcn_perm(u3, u2, 0x07060302);  // [L2, L3]
    r.u[2] = __builtin_amdgcn_perm(u5, u4, 0x07060302);  // [L4, L5]
    r.u[3] = __builtin_amdgcn_perm(u7, u6, 0x07060302);  // [L6, L7]
    return r.s;
}

// ---- GEMM, register-pipelined, barrier-free ----
__global__ __launch_bounds__(256, 2) void gemm_kernel(const unsigned short* __restrict__ T,
                                                      const unsigned short* __restrict__ Bt,
                                                      float* __restrict__ out) {
    const int tid  = threadIdx.x;
    const int lane = tid & 63;
    const int wave = tid >> 6;
    const int n0w = blockIdx.x * BN + wave * 64;   // this wave's 64-col n range
    const int m0  = blockIdx.y * BM;               // block's 64-row m range

    const int l16  = lane & 15;
    const int quad = lane >> 4;

    // element offsets (int, max ~8.4M): 8 B-frag offsets, 8 T offsets
    int boff[8], toff[8];
    #pragma unroll
    for (int tn = 0; tn < 4; ++tn)
        #pragma unroll
        for (int k2 = 0; k2 < 2; ++k2)
            boff[tn * 2 + k2] = (n0w + tn * 16 + l16) * K_DIM + k2 * 32 + quad * 8;
    #pragma unroll
    for (int tt = 0; tt < 4; ++tt)
        #pragma unroll
        for (int k2 = 0; k2 < 2; ++k2)
            toff[tt * 2 + k2] = (m0 + tt * 16 + l16) * I_DIM + k2 * 4 + quad;

    float4v acc[4][4];
    const float4v zero = {0.f, 0.f, 0.f, 0.f};
    #pragma unroll
    for (int a = 0; a < 4; ++a)
        #pragma unroll
        for (int b = 0; b < 4; ++b) acc[a][b] = zero;

    // prologue: load step-0 fragments into registers
    short8 bcur[8];
    unsigned short tcur[8];
    #pragma unroll
    for (int j = 0; j < 8; ++j) {
        bcur[j] = *(const short8*)(Bt + boff[j]);
        tcur[j] = T[toff[j]];
        boff[j] += BK;       // advance to step 1
        toff[j] += 8;
    }

    for (int s = 0; s < NSTEP; ++s) {
        // issue next step's loads (no wait; compiler waits before first use)
        short8 bnxt[8];
        unsigned short tnxt[8];
        if (s + 1 < NSTEP) {
            #pragma unroll
            for (int j = 0; j < 8; ++j) {
                bnxt[j] = *(const short8*)(Bt + boff[j]);
                tnxt[j] = T[toff[j]];
                boff[j] += BK;
                toff[j] += 8;
            }
        }

        // compute: expand A-frags in registers, 32 MFMAs
        #pragma unroll
        for (int k2 = 0; k2 < 2; ++k2) {
            #pragma unroll
            for (int tt = 0; tt < 4; ++tt) {
                const short8 af = lucas_frag(tcur[tt * 2 + k2]);
                #pragma unroll
                for (int tn = 0; tn < 4; ++tn)
                    acc[tt][tn] = __builtin_amdgcn_mfma_f32_16x16x32_bf16(
                        af, bcur[tn * 2 + k2], acc[tt][tn], 0, 0, 0);
            }
        }

        #pragma unroll
        for (int j = 0; j < 8; ++j) { bcur[j] = bnxt[j]; tcur[j] = tnxt[j]; }
    }

    // epilogue: D[row=(lane>>4)*4+r][col=lane&15] (verified R1-R3)
    #pragma unroll
    for (int tt = 0; tt < 4; ++tt) {
        #pragma unroll
        for (int tn = 0; tn < 4; ++tn) {
            const int col = n0w + tn * 16 + l16;
            #pragma unroll
            for (int r = 0; r < 4; ++r) {
                const int row = m0 + tt * 16 + quad * 4 + r;
                out[(size_t)row * O_DIM + col] = acc[tt][tn][r];
            }
        }
    }
}

// ---- fallback (tiny workspace): direct fp32 ----
__global__ __launch_bounds__(256) void naive_kernel(const float* __restrict__ x,
                                                    const float* __restrict__ c,
                                                    float* __restrict__ out) {
    int idx = blockIdx.x * 256 + threadIdx.x;   // one (b,o)
    int b = idx >> 10;
    int o = idx & 1023;
    const float* xb = x + (size_t)b * I_DIM;
    float acc = 0.f;
    for (int i = 0; i < I_DIM; ++i) {
        float t = tanhf(xb[i]);
        float L[8];
        L[0] = 2.0f; L[1] = t;
        #pragma unroll
        for (int d = 2; d < 8; ++d) L[d] = t * L[d - 1] + L[d - 2];
        const float* cc = c + (size_t)i * 8192 + o * 8;
        #pragma unroll
        for (int d = 0; d < 8; ++d) acc += L[d] * cc[d];
    }
    out[idx] = acc;
}

extern "C" void kernel_launch(void* const* d_in, const int* in_sizes, int n_in,
                              void* d_out, int out_size, void* d_ws, size_t ws_size,
                              hipStream_t stream) {
    const float* x      = (const float*)d_in[0];
    const float* coeffs = (const float*)d_in[1];
    float* out = (float*)d_out;

    const size_t btBytes = (size_t)O_DIM * K_DIM * sizeof(unsigned short);   // 16 MiB
    const size_t tBytes  = (size_t)M_DIM * I_DIM * sizeof(unsigned short);   // 16 MiB

    if (ws_size >= btBytes + tBytes) {
        unsigned short* Bt = (unsigned short*)d_ws;
        unsigned short* T  = (unsigned short*)((char*)d_ws + btBytes);

        const int tBlocks = (M_DIM * I_DIM) / (4 * 256);   // 8192
        const int bBlocks = (I_DIM * O_DIM) / 256;          // 4096
        prep_kernel<<<tBlocks + bBlocks, 256, 0, stream>>>(x, coeffs, T, Bt);

        dim3 grid(O_DIM / BN, M_DIM / BM);   // (4, 128): XCD = (x+4y)%8 -> 1 B-panel/XCD
        gemm_kernel<<<grid, 256, 0, stream>>>(T, Bt, out);
    } else {
        naive_kernel<<<(M_DIM * O_DIM) / 256, 256, 0, stream>>>(x, coeffs, out);
    }
}

// Round 5
// 254.269 us; speedup vs baseline: 2.1887x; 2.1887x over previous
//
#include <hip/hip_runtime.h>
#include <hip/hip_bf16.h>

// ---------------------------------------------------------------------------
// LucasKANLayer fused: y[b,o] = sum_i sum_d L_d(tanh(x[b,i])) * C[i,o,d]
// R5 = R3 (best: LDS-staged B, register Lucas expansion, 1 barrier/step,
// 4 blocks/CU) + two fixes:
//  (a) grid (x=n-panel, y=m): XCD = linear%8 = n-panel -> each XCD's L2 keeps
//      its 2 MB B-panel resident (R3 grid had XCD=m%8: all panels thrashed L2,
//      FETCH 80 MB, prefetch at HBM latency).
//  (b) cheaper expansion: v_cvt_pk_bf16_f32 (fallback: truncation+perm) and
//      T pre-permuted in groups of 8 so one ds_read_b32 feeds both k2 frags.
// ---------------------------------------------------------------------------

typedef __attribute__((ext_vector_type(8)))  short  short8;    // bf16x8 MFMA frag
typedef __attribute__((ext_vector_type(4)))  unsigned short ushort4v;
typedef __attribute__((ext_vector_type(8)))  unsigned short ushort8;
typedef __attribute__((ext_vector_type(4)))  float  float4v;
typedef __attribute__((ext_vector_type(4)))  unsigned int uint4v;

#define M_DIM 8192
#define I_DIM 1024
#define O_DIM 1024
#define K_DIM 8192   // I_DIM * 8
#define BM 64
#define BN 128
#define BK 64        // 8 i-values per K-step
#define NSTEP (K_DIM / BK)

// round-to-nearest-even fp32 -> bf16 bits (prep kernel)
__device__ __forceinline__ unsigned short f2bf(float f) {
    unsigned int u = __float_as_uint(f);
    u += 0x7FFFu + ((u >> 16) & 1u);
    return (unsigned short)(u >> 16);
}

// ---- fused prep ----
// T[b][group g][slot]: slot 2p   = t(i = g*8+p)      (p=0..3)
//                      slot 2p+1 = t(i = g*8+p+4)
// so a ds_read_b32 at u16-offset quad*2 yields {lo=t(quad), hi=t(quad+4)}.
// Bt[o][i*8+d] = bf16(coeffs[i][o][d]).
__global__ __launch_bounds__(256) void prep_kernel(const float* __restrict__ x,
                                                   const float* __restrict__ c,
                                                   unsigned short* __restrict__ T,
                                                   unsigned short* __restrict__ Bt) {
    int bid = blockIdx.x;
    const int tPart = (M_DIM * I_DIM) / (8 * 256);   // 4096 blocks, 8 elems/thread
    if (bid < tPart) {
        int idx = (bid * 256 + threadIdx.x) * 8;     // aligned 8-group
        float4v v0 = *(const float4v*)(x + idx);
        float4v v1 = *(const float4v*)(x + idx + 4);
        unsigned short t[8];
        t[0] = f2bf(tanhf(v0[0])); t[1] = f2bf(tanhf(v0[1]));
        t[2] = f2bf(tanhf(v0[2])); t[3] = f2bf(tanhf(v0[3]));
        t[4] = f2bf(tanhf(v1[0])); t[5] = f2bf(tanhf(v1[1]));
        t[6] = f2bf(tanhf(v1[2])); t[7] = f2bf(tanhf(v1[3]));
        ushort8 o;
        #pragma unroll
        for (int p = 0; p < 4; ++p) { o[2 * p] = t[p]; o[2 * p + 1] = t[p + 4]; }
        *(ushort8*)(T + idx) = o;
    } else {
        int idx = (bid - tPart) * 256 + threadIdx.x; // one (i,o) per thread
        int i = idx >> 10;
        int o = idx & 1023;
        const float* src = c + (size_t)i * 8192 + o * 8;
        float4v lo = *(const float4v*)(src);
        float4v hi = *(const float4v*)(src + 4);
        ushort8 v;
        v[0] = f2bf(lo[0]); v[1] = f2bf(lo[1]); v[2] = f2bf(lo[2]); v[3] = f2bf(lo[3]);
        v[4] = f2bf(hi[0]); v[5] = f2bf(hi[1]); v[6] = f2bf(hi[2]); v[7] = f2bf(hi[3]);
        *(ushort8*)(Bt + (size_t)o * K_DIM + i * 8) = v;
    }
}

// Lucas A-fragment {2, t, L2..L7} packed bf16x8 from bf16 t-bits tb (low 16).
__device__ __forceinline__ short8 lucas_frag(unsigned int tb) {
    const float t = __uint_as_float(tb << 16);
    const float L2v = fmaf(t, t, 2.0f);
    const float L3v = fmaf(t, L2v, t);
    const float L4v = fmaf(t, L3v, L2v);
    const float L5v = fmaf(t, L4v, L3v);
    const float L6v = fmaf(t, L5v, L4v);
    const float L7v = fmaf(t, L6v, L5v);
    union { uint4v u; short8 s; } r;
#if __has_builtin(__builtin_amdgcn_cvt_pk_bf16_f32)
    {   // RNE packed converts: 4 inst replace 6 add + 3 perm + or
        auto p0 = __builtin_amdgcn_cvt_pk_bf16_f32(2.0f, t);
        auto p1 = __builtin_amdgcn_cvt_pk_bf16_f32(L2v, L3v);
        auto p2 = __builtin_amdgcn_cvt_pk_bf16_f32(L4v, L5v);
        auto p3 = __builtin_amdgcn_cvt_pk_bf16_f32(L6v, L7v);
        __builtin_memcpy(&r.u[0], &p0, 4);
        __builtin_memcpy(&r.u[1], &p1, 4);
        __builtin_memcpy(&r.u[2], &p2, 4);
        __builtin_memcpy(&r.u[3], &p3, 4);
    }
#else
    {   // truncation pack (bias ~ -y/512, absmax ~0.004 < 6.9e-3 threshold)
        r.u[0] = 0x4000u | (tb << 16);
        r.u[1] = __builtin_amdgcn_perm(__float_as_uint(L3v), __float_as_uint(L2v), 0x07060302);
        r.u[2] = __builtin_amdgcn_perm(__float_as_uint(L5v), __float_as_uint(L4v), 0x07060302);
        r.u[3] = __builtin_amdgcn_perm(__float_as_uint(L7v), __float_as_uint(L6v), 0x07060302);
    }
#endif
    return r.s;
}

// ---- fused GEMM: out[m][n] = sum_k A[m][k] * Bt[n][k], A expanded in regs ----
__global__ __launch_bounds__(256, 4) void gemm_kernel(const unsigned short* __restrict__ T,
                                                      const unsigned short* __restrict__ Bt,
                                                      float* __restrict__ out) {
    __shared__ unsigned short Bs[2][BN * BK];   // 32 KB, XOR-swizzled, dbuf
    __shared__ unsigned short Ts[2][BM * 8];    // 2 KB, dbuf (permuted 8-groups)

    const int tid  = threadIdx.x;
    const int lane = tid & 63;
    const int wave = tid >> 6;
    const int n0 = blockIdx.x * BN;   // x = n-panel (8): XCD = linear%8 = n-panel
    const int m0 = blockIdx.y * BM;   // y = m (128)

    const int wm0  = (wave >> 1) * 32;   // wave tile 32 m x 64 n
    const int wn0  = (wave & 1) * 64;
    const int l16  = lane & 15;
    const int quad = lane >> 4;

    // staging lane mapping: row-sub srow, XOR-swizzled chunk
    const int srow   = lane >> 3;            // 0..7
    const int il     = lane & 7;
    const int gchunk = il ^ srow;            // global 16B chunk this lane fetches

    float4v acc[2][4];
    const float4v zero = {0.f, 0.f, 0.f, 0.f};
    #pragma unroll
    for (int a = 0; a < 2; ++a)
        #pragma unroll
        for (int b = 0; b < 4; ++b) acc[a][b] = zero;

    // ---- prologue: stage Bs[0], Ts[0] for kt=0 ----
    #pragma unroll
    for (int r = 0; r < 4; ++r) {
        const int rowb = r * 32 + wave * 8;
        const unsigned short* gB = Bt + (size_t)(n0 + rowb + srow) * K_DIM + gchunk * 8;
        __builtin_amdgcn_global_load_lds(
            (const __attribute__((address_space(1))) unsigned int*)gB,
            (__attribute__((address_space(3))) unsigned int*)&Bs[0][rowb * BK], 16, 0, 0);
    }
    if (wave == 0) {
        const unsigned short* gT = T + (size_t)(m0 + lane) * I_DIM;
        __builtin_amdgcn_global_load_lds(
            (const __attribute__((address_space(1))) unsigned int*)gT,
            (__attribute__((address_space(3))) unsigned int*)&Ts[0][0], 16, 0, 0);
    }
    __syncthreads();

    int cur = 0;
    for (int s = 0; s < NSTEP; ++s) {
        const int nxt = cur ^ 1;

        // ---- prefetch next step (drained by the end-of-step barrier) ----
        if (s + 1 < NSTEP) {
            const int kt = (s + 1) * BK;
            #pragma unroll
            for (int r = 0; r < 4; ++r) {
                const int rowb = r * 32 + wave * 8;
                const unsigned short* gB = Bt + (size_t)(n0 + rowb + srow) * K_DIM + kt + gchunk * 8;
                __builtin_amdgcn_global_load_lds(
                    (const __attribute__((address_space(1))) unsigned int*)gB,
                    (__attribute__((address_space(3))) unsigned int*)&Bs[nxt][rowb * BK], 16, 0, 0);
            }
            if (wave == 0) {
                const unsigned short* gT = T + (size_t)(m0 + lane) * I_DIM + kt / 8;
                __builtin_amdgcn_global_load_lds(
                    (const __attribute__((address_space(1))) unsigned int*)gT,
                    (__attribute__((address_space(3))) unsigned int*)&Ts[nxt][0], 16, 0, 0);
            }
        }

        // ---- t-values (one b32 per m-tile: lo=t(quad)=k2:0, hi=t(quad+4)=k2:1) ----
        unsigned int tw[2];
        #pragma unroll
        for (int tt = 0; tt < 2; ++tt)
            tw[tt] = *(const unsigned int*)&Ts[cur][(wm0 + tt * 16 + l16) * 8 + quad * 2];

        #pragma unroll
        for (int k2 = 0; k2 < 2; ++k2) {
            short8 af[2];
            af[0] = lucas_frag(k2 ? (tw[0] >> 16) : (tw[0] & 0xffffu));
            af[1] = lucas_frag(k2 ? (tw[1] >> 16) : (tw[1] & 0xffffu));
            short8 bfr[4];
            #pragma unroll
            for (int tn = 0; tn < 4; ++tn) {
                const int brow = wn0 + tn * 16 + l16;
                bfr[tn] = *(const short8*)&Bs[cur][brow * BK + (((k2 * 4 + quad) ^ (l16 & 7)) * 8)];
            }
            #pragma unroll
            for (int tt = 0; tt < 2; ++tt)
                #pragma unroll
                for (int tn = 0; tn < 4; ++tn)
                    acc[tt][tn] = __builtin_amdgcn_mfma_f32_16x16x32_bf16(
                        af[tt], bfr[tn], acc[tt][tn], 0, 0, 0);
        }

        __syncthreads();   // drains prefetch + protects Bs/Ts swap
        cur = nxt;
    }

    // ---- epilogue: D[row=(lane>>4)*4+r][col=lane&15] (verified R1-R4) ----
    #pragma unroll
    for (int tt = 0; tt < 2; ++tt) {
        #pragma unroll
        for (int tn = 0; tn < 4; ++tn) {
            const int col = n0 + wn0 + tn * 16 + l16;
            #pragma unroll
            for (int r = 0; r < 4; ++r) {
                const int row = m0 + wm0 + tt * 16 + quad * 4 + r;
                out[(size_t)row * O_DIM + col] = acc[tt][tn][r];
            }
        }
    }
}

// ---- fallback (tiny workspace): direct fp32 ----
__global__ __launch_bounds__(256) void naive_kernel(const float* __restrict__ x,
                                                    const float* __restrict__ c,
                                                    float* __restrict__ out) {
    int idx = blockIdx.x * 256 + threadIdx.x;   // one (b,o)
    int b = idx >> 10;
    int o = idx & 1023;
    const float* xb = x + (size_t)b * I_DIM;
    float acc = 0.f;
    for (int i = 0; i < I_DIM; ++i) {
        float t = tanhf(xb[i]);
        float L[8];
        L[0] = 2.0f; L[1] = t;
        #pragma unroll
        for (int d = 2; d < 8; ++d) L[d] = t * L[d - 1] + L[d - 2];
        const float* cc = c + (size_t)i * 8192 + o * 8;
        #pragma unroll
        for (int d = 0; d < 8; ++d) acc += L[d] * cc[d];
    }
    out[idx] = acc;
}

extern "C" void kernel_launch(void* const* d_in, const int* in_sizes, int n_in,
                              void* d_out, int out_size, void* d_ws, size_t ws_size,
                              hipStream_t stream) {
    const float* x      = (const float*)d_in[0];
    const float* coeffs = (const float*)d_in[1];
    float* out = (float*)d_out;

    const size_t btBytes = (size_t)O_DIM * K_DIM * sizeof(unsigned short);   // 16 MiB
    const size_t tBytes  = (size_t)M_DIM * I_DIM * sizeof(unsigned short);   // 16 MiB

    if (ws_size >= btBytes + tBytes) {
        unsigned short* Bt = (unsigned short*)d_ws;
        unsigned short* T  = (unsigned short*)((char*)d_ws + btBytes);

        const int tBlocks = (M_DIM * I_DIM) / (8 * 256);   // 4096
        const int bBlocks = (I_DIM * O_DIM) / 256;          // 4096
        prep_kernel<<<tBlocks + bBlocks, 256, 0, stream>>>(x, coeffs, T, Bt);

        dim3 grid(O_DIM / BN, M_DIM / BM);   // (8, 128): XCD = linear%8 = n-panel
        gemm_kernel<<<grid, 256, 0, stream>>>(T, Bt, out);
    } else {
        naive_kernel<<<(M_DIM * O_DIM) / 256, 256, 0, stream>>>(x, coeffs, out);
    }
}

// Round 6
// 254.090 us; speedup vs baseline: 2.1903x; 1.0007x over previous
//
#include <hip/hip_runtime.h>
#include <hip/hip_bf16.h>

// ---------------------------------------------------------------------------
// LucasKANLayer fused: y[b,o] = sum_i sum_d L_d(tanh(x[b,i])) * C[i,o,d]
// R6 = R5 + wave tile 64m x 64n (4x4 acc): LDS reads per MFMA halve (0.25),
// 32 independent MFMAs between barriers (2x ILP). Block 128m x 128n (4 waves),
// K split in 2 (grid z): 1024 blocks = 4 blocks/CU (36 KB LDS x4 fits 160).
// Epilogue: fp32 atomicAdd into zero-initialized out (2 writers/cell).
// XCD mapping: linear%8 = blockIdx.x = n-panel for all z (L2-resident panel).
// ---------------------------------------------------------------------------

typedef __attribute__((ext_vector_type(8)))  short  short8;    // bf16x8 MFMA frag
typedef __attribute__((ext_vector_type(4)))  unsigned short ushort4v;
typedef __attribute__((ext_vector_type(8)))  unsigned short ushort8;
typedef __attribute__((ext_vector_type(4)))  float  float4v;
typedef __attribute__((ext_vector_type(4)))  unsigned int uint4v;

#define M_DIM 8192
#define I_DIM 1024
#define O_DIM 1024
#define K_DIM 8192   // I_DIM * 8
#define BM 128
#define BN 128
#define BK 64        // 8 i-values per K-step
#define KSPLIT 2
#define KHALF (K_DIM / KSPLIT)
#define NSTEP (KHALF / BK)   // 64

// round-to-nearest-even fp32 -> bf16 bits (prep kernel)
__device__ __forceinline__ unsigned short f2bf(float f) {
    unsigned int u = __float_as_uint(f);
    u += 0x7FFFu + ((u >> 16) & 1u);
    return (unsigned short)(u >> 16);
}

// ---- zero out (harness poisons d_out with 0xAA; atomics need 0) ----
__global__ __launch_bounds__(256) void zero_kernel(float* __restrict__ p) {
    int idx = (blockIdx.x * 256 + threadIdx.x) * 4;
    const float4v z = {0.f, 0.f, 0.f, 0.f};
    *(float4v*)(p + idx) = z;
}

// ---- fused prep ----
// T[b][group g][slot]: slot 2p = t(i=g*8+p), slot 2p+1 = t(i=g*8+p+4)
// so ds_read_b32 at u16-offset quad*2 gives {lo=t(quad), hi=t(quad+4)}.
// Bt[o][i*8+d] = bf16(coeffs[i][o][d]).
__global__ __launch_bounds__(256) void prep_kernel(const float* __restrict__ x,
                                                   const float* __restrict__ c,
                                                   unsigned short* __restrict__ T,
                                                   unsigned short* __restrict__ Bt) {
    int bid = blockIdx.x;
    const int tPart = (M_DIM * I_DIM) / (8 * 256);   // 4096 blocks, 8 elems/thread
    if (bid < tPart) {
        int idx = (bid * 256 + threadIdx.x) * 8;
        float4v v0 = *(const float4v*)(x + idx);
        float4v v1 = *(const float4v*)(x + idx + 4);
        unsigned short t[8];
        t[0] = f2bf(tanhf(v0[0])); t[1] = f2bf(tanhf(v0[1]));
        t[2] = f2bf(tanhf(v0[2])); t[3] = f2bf(tanhf(v0[3]));
        t[4] = f2bf(tanhf(v1[0])); t[5] = f2bf(tanhf(v1[1]));
        t[6] = f2bf(tanhf(v1[2])); t[7] = f2bf(tanhf(v1[3]));
        ushort8 o;
        #pragma unroll
        for (int p = 0; p < 4; ++p) { o[2 * p] = t[p]; o[2 * p + 1] = t[p + 4]; }
        *(ushort8*)(T + idx) = o;
    } else {
        int idx = (bid - tPart) * 256 + threadIdx.x; // one (i,o) per thread
        int i = idx >> 10;
        int o = idx & 1023;
        const float* src = c + (size_t)i * 8192 + o * 8;
        float4v lo = *(const float4v*)(src);
        float4v hi = *(const float4v*)(src + 4);
        ushort8 v;
        v[0] = f2bf(lo[0]); v[1] = f2bf(lo[1]); v[2] = f2bf(lo[2]); v[3] = f2bf(lo[3]);
        v[4] = f2bf(hi[0]); v[5] = f2bf(hi[1]); v[6] = f2bf(hi[2]); v[7] = f2bf(hi[3]);
        *(ushort8*)(Bt + (size_t)o * K_DIM + i * 8) = v;
    }
}

// Lucas A-fragment {2, t, L2..L7} packed bf16x8 from bf16 t-bits tb (low 16).
__device__ __forceinline__ short8 lucas_frag(unsigned int tb) {
    const float t = __uint_as_float(tb << 16);
    const float L2v = fmaf(t, t, 2.0f);
    const float L3v = fmaf(t, L2v, t);
    const float L4v = fmaf(t, L3v, L2v);
    const float L5v = fmaf(t, L4v, L3v);
    const float L6v = fmaf(t, L5v, L4v);
    const float L7v = fmaf(t, L6v, L5v);
    union { uint4v u; short8 s; } r;
#if __has_builtin(__builtin_amdgcn_cvt_pk_bf16_f32)
    {
        auto p0 = __builtin_amdgcn_cvt_pk_bf16_f32(2.0f, t);
        auto p1 = __builtin_amdgcn_cvt_pk_bf16_f32(L2v, L3v);
        auto p2 = __builtin_amdgcn_cvt_pk_bf16_f32(L4v, L5v);
        auto p3 = __builtin_amdgcn_cvt_pk_bf16_f32(L6v, L7v);
        __builtin_memcpy(&r.u[0], &p0, 4);
        __builtin_memcpy(&r.u[1], &p1, 4);
        __builtin_memcpy(&r.u[2], &p2, 4);
        __builtin_memcpy(&r.u[3], &p3, 4);
    }
#else
    {
        r.u[0] = 0x4000u | (tb << 16);
        r.u[1] = __builtin_amdgcn_perm(__float_as_uint(L3v), __float_as_uint(L2v), 0x07060302);
        r.u[2] = __builtin_amdgcn_perm(__float_as_uint(L5v), __float_as_uint(L4v), 0x07060302);
        r.u[3] = __builtin_amdgcn_perm(__float_as_uint(L7v), __float_as_uint(L6v), 0x07060302);
    }
#endif
    return r.s;
}

// ---- fused GEMM: out[m][n] += sum_{k in half} A[m][k] * Bt[n][k] ----
__global__ __launch_bounds__(256, 4) void gemm_kernel(const unsigned short* __restrict__ T,
                                                      const unsigned short* __restrict__ Bt,
                                                      float* __restrict__ out) {
    __shared__ unsigned short Bs[2][BN * BK];   // 32 KB, XOR-swizzled, dbuf
    __shared__ unsigned short Ts[2][BM * 8];    // 4 KB, dbuf (permuted 8-groups)

    const int tid  = threadIdx.x;
    const int lane = tid & 63;
    const int wave = tid >> 6;
    const int n0 = blockIdx.x * BN;        // x = n-panel (8): XCD = linear%8 = x
    const int m0 = blockIdx.y * BM;        // y = m (64)
    const int k0 = blockIdx.z * KHALF;     // z = K half (2)

    const int wm0  = (wave >> 1) * 64;     // wave tile 64 m x 64 n
    const int wn0  = (wave & 1) * 64;
    const int l16  = lane & 15;
    const int quad = lane >> 4;

    const int srow   = lane >> 3;          // 0..7
    const int il     = lane & 7;
    const int gchunk = il ^ srow;          // XOR-swizzled global 16B chunk

    float4v acc[4][4];
    const float4v zero = {0.f, 0.f, 0.f, 0.f};
    #pragma unroll
    for (int a = 0; a < 4; ++a)
        #pragma unroll
        for (int b = 0; b < 4; ++b) acc[a][b] = zero;

    // ---- prologue: stage Bs[0], Ts[0] for s=0 ----
    #pragma unroll
    for (int r = 0; r < 4; ++r) {
        const int rowb = r * 32 + wave * 8;
        const unsigned short* gB = Bt + (size_t)(n0 + rowb + srow) * K_DIM + k0 + gchunk * 8;
        __builtin_amdgcn_global_load_lds(
            (const __attribute__((address_space(1))) unsigned int*)gB,
            (__attribute__((address_space(3))) unsigned int*)&Bs[0][rowb * BK], 16, 0, 0);
    }
    if (wave < 2) {
        const unsigned short* gT = T + (size_t)(m0 + wave * 64 + lane) * I_DIM + k0 / 8;
        __builtin_amdgcn_global_load_lds(
            (const __attribute__((address_space(1))) unsigned int*)gT,
            (__attribute__((address_space(3))) unsigned int*)&Ts[0][wave * 64 * 8], 16, 0, 0);
    }
    __syncthreads();

    int cur = 0;
    for (int s = 0; s < NSTEP; ++s) {
        const int nxt = cur ^ 1;

        // ---- prefetch next step (drained by end-of-step barrier) ----
        if (s + 1 < NSTEP) {
            const int kt = k0 + (s + 1) * BK;
            #pragma unroll
            for (int r = 0; r < 4; ++r) {
                const int rowb = r * 32 + wave * 8;
                const unsigned short* gB = Bt + (size_t)(n0 + rowb + srow) * K_DIM + kt + gchunk * 8;
                __builtin_amdgcn_global_load_lds(
                    (const __attribute__((address_space(1))) unsigned int*)gB,
                    (__attribute__((address_space(3))) unsigned int*)&Bs[nxt][rowb * BK], 16, 0, 0);
            }
            if (wave < 2) {
                const unsigned short* gT = T + (size_t)(m0 + wave * 64 + lane) * I_DIM + kt / 8;
                __builtin_amdgcn_global_load_lds(
                    (const __attribute__((address_space(1))) unsigned int*)gT,
                    (__attribute__((address_space(3))) unsigned int*)&Ts[nxt][wave * 64 * 8], 16, 0, 0);
            }
        }

        // ---- t-values: one b32 per m-tile {lo=t(quad)->k2=0, hi=t(quad+4)->k2=1} ----
        unsigned int tw[4];
        #pragma unroll
        for (int tt = 0; tt < 4; ++tt)
            tw[tt] = *(const unsigned int*)&Ts[cur][(wm0 + tt * 16 + l16) * 8 + quad * 2];

        #pragma unroll
        for (int k2 = 0; k2 < 2; ++k2) {
            short8 bfr[4];
            #pragma unroll
            for (int tn = 0; tn < 4; ++tn) {
                const int brow = wn0 + tn * 16 + l16;
                bfr[tn] = *(const short8*)&Bs[cur][brow * BK + (((k2 * 4 + quad) ^ (l16 & 7)) * 8)];
            }
            #pragma unroll
            for (int tt = 0; tt < 4; ++tt) {
                const short8 af = lucas_frag(k2 ? (tw[tt] >> 16) : (tw[tt] & 0xffffu));
                #pragma unroll
                for (int tn = 0; tn < 4; ++tn)
                    acc[tt][tn] = __builtin_amdgcn_mfma_f32_16x16x32_bf16(
                        af, bfr[tn], acc[tt][tn], 0, 0, 0);
            }
        }

        __syncthreads();   // drains prefetch + protects Bs/Ts swap
        cur = nxt;
    }

    // ---- epilogue: atomic accumulate (2 K-half writers per cell) ----
    // D[row=(lane>>4)*4+r][col=lane&15] (layout verified R1-R5)
    #pragma unroll
    for (int tt = 0; tt < 4; ++tt) {
        #pragma unroll
        for (int tn = 0; tn < 4; ++tn) {
            const int col = n0 + wn0 + tn * 16 + l16;
            #pragma unroll
            for (int r = 0; r < 4; ++r) {
                const int row = m0 + wm0 + tt * 16 + quad * 4 + r;
                atomicAdd(&out[(size_t)row * O_DIM + col], acc[tt][tn][r]);
            }
        }
    }
}

// ---- fallback (tiny workspace): direct fp32 ----
__global__ __launch_bounds__(256) void naive_kernel(const float* __restrict__ x,
                                                    const float* __restrict__ c,
                                                    float* __restrict__ out) {
    int idx = blockIdx.x * 256 + threadIdx.x;   // one (b,o)
    int b = idx >> 10;
    int o = idx & 1023;
    const float* xb = x + (size_t)b * I_DIM;
    float acc = 0.f;
    for (int i = 0; i < I_DIM; ++i) {
        float t = tanhf(xb[i]);
        float L[8];
        L[0] = 2.0f; L[1] = t;
        #pragma unroll
        for (int d = 2; d < 8; ++d) L[d] = t * L[d - 1] + L[d - 2];
        const float* cc = c + (size_t)i * 8192 + o * 8;
        #pragma unroll
        for (int d = 0; d < 8; ++d) acc += L[d] * cc[d];
    }
    out[idx] = acc;
}

extern "C" void kernel_launch(void* const* d_in, const int* in_sizes, int n_in,
                              void* d_out, int out_size, void* d_ws, size_t ws_size,
                              hipStream_t stream) {
    const float* x      = (const float*)d_in[0];
    const float* coeffs = (const float*)d_in[1];
    float* out = (float*)d_out;

    const size_t btBytes = (size_t)O_DIM * K_DIM * sizeof(unsigned short);   // 16 MiB
    const size_t tBytes  = (size_t)M_DIM * I_DIM * sizeof(unsigned short);   // 16 MiB

    if (ws_size >= btBytes + tBytes) {
        unsigned short* Bt = (unsigned short*)d_ws;
        unsigned short* T  = (unsigned short*)((char*)d_ws + btBytes);

        zero_kernel<<<(M_DIM * O_DIM) / (4 * 256), 256, 0, stream>>>(out);

        const int tBlocks = (M_DIM * I_DIM) / (8 * 256);   // 4096
        const int bBlocks = (I_DIM * O_DIM) / 256;          // 4096
        prep_kernel<<<tBlocks + bBlocks, 256, 0, stream>>>(x, coeffs, T, Bt);

        dim3 grid(O_DIM / BN, M_DIM / BM, KSPLIT);   // (8, 64, 2): XCD = x
        gemm_kernel<<<grid, 256, 0, stream>>>(T, Bt, out);
    } else {
        naive_kernel<<<(M_DIM * O_DIM) / 256, 256, 0, stream>>>(x, coeffs, out);
    }
}